// Round 11
// baseline (1581.236 us; speedup 1.0000x reference)
//
#include <hip/hip_runtime.h>
#include <hip/hip_bf16.h>

#define NROWS 32768
#define DIM   512
#define NQ    8
#define NBINS 2048

#define MARGIN 1.0f        // ~20 sigma of bf16 phase-1 noise (validated rounds 5/7/8/9/10)

typedef __attribute__((ext_vector_type(8))) short short8v;
typedef __attribute__((ext_vector_type(4))) float f32x4;

__device__ inline unsigned short f2bf(float x) {
    __hip_bfloat16 h = __float2bfloat16(x);
    return *reinterpret_cast<unsigned short*>(&h);
}

typedef __attribute__((address_space(3))) void lds_t;
typedef __attribute__((address_space(1))) const void gbl_t;
__device__ inline void gload16(const void* g, void* l) {
    __builtin_amdgcn_global_load_lds((gbl_t*)g, (lds_t*)l, 16, 0, 0);
}

// ---------------------------------------------------------------------------
// numpy pairwise-sum combine (validated round 4)
__device__ inline float pw_combine(float s) {
#pragma unroll
    for (int m = 1; m <= 16; m <<= 1) {
        float o = __shfl_xor(s, m, 64);
        s = __fadd_rn(s, o);
    }
    return s;
}

// csq = np.sum(c*c,-1) exact numpy f32 pairwise semantics (validated round 4)
__global__ __launch_bounds__(256) void k_csq(const float* __restrict__ cb,
                                             float* __restrict__ csq32) {
    int row = blockIdx.x * 4 + (threadIdx.x >> 6);
    int lane = threadIdx.x & 63;
    const float* cp = cb + (size_t)row * DIM;
    float s = 0.0f;
    if (lane < 32) {
        int base = (lane >> 3) * 128 + (lane & 7);
        float e = cp[base];
        s = __fmul_rn(e, e);
#pragma unroll
        for (int m = 1; m < 16; ++m) {
            float e2 = cp[base + 8 * m];
            s = __fadd_rn(s, __fmul_rn(e2, e2));
        }
    }
    s = pw_combine(s);
    if (lane == 0) csq32[row] = s;
}

// ---------------------------------------------------------------------------
// codebooks fp32 -> bf16 (one shot, all stages)
__global__ __launch_bounds__(256) void k_cbf(const float* __restrict__ cb,
                                             unsigned short* __restrict__ o) {
    size_t base = ((size_t)blockIdx.x * 256 + threadIdx.x) * 8;
    float4 a = *(const float4*)(cb + base);
    float4 b = *(const float4*)(cb + base + 4);
    short8v v;
    v[0] = f2bf(a.x); v[1] = f2bf(a.y); v[2] = f2bf(a.z); v[3] = f2bf(a.w);
    v[4] = f2bf(b.x); v[5] = f2bf(b.y); v[6] = f2bf(b.z); v[7] = f2bf(b.w);
    *(short8v*)(o + base) = v;
}

// ---------------------------------------------------------------------------
// initial residual (= hidden) + np-exact rsq + bf16 copy for the MFMA phase.
__global__ __launch_bounds__(128) void k_init(const float* __restrict__ h,
                                              float* __restrict__ rout,
                                              float* __restrict__ rsq,
                                              unsigned short* __restrict__ ahi) {
    int row = blockIdx.x;
    int t = threadIdx.x;
    __shared__ float sq[DIM];
    float4 r = *(const float4*)(h + (size_t)row * DIM + t * 4);
    *(float4*)(rout + (size_t)row * DIM + t * 4) = r;
    ushort4 hv;
    hv.x = f2bf(r.x); hv.y = f2bf(r.y); hv.z = f2bf(r.z); hv.w = f2bf(r.w);
    *(ushort4*)(ahi + (size_t)row * DIM + t * 4) = hv;
    sq[t * 4 + 0] = __fmul_rn(r.x, r.x);
    sq[t * 4 + 1] = __fmul_rn(r.y, r.y);
    sq[t * 4 + 2] = __fmul_rn(r.z, r.z);
    sq[t * 4 + 3] = __fmul_rn(r.w, r.w);
    __syncthreads();
    if (t < 32) {
        int base = (t >> 3) * 128 + (t & 7);
        float s = sq[base];
#pragma unroll
        for (int m = 1; m < 16; ++m) s = __fadd_rn(s, sq[base + 8 * m]);
        s = pw_combine(s);
        if (t == 0) rsq[row] = s;
    }
}

// ---------------------------------------------------------------------------
// phase-1: bf16 MFMA GEMM, 256x256 tile, BK=32, 8 waves (128x64 out each,
// acc[8][4] = 128 AGPR). COUNTED-VMCNT 3-tile-deep pipeline (T3/T4):
// 4 LDS K-tile buffers; compute tile t from buf[t&3] while tiles t+1,t+2
// remain in flight; stage tile t+3 after the per-iteration raw s_barrier.
// vmcnt(8) steady state -- never drained to 0 in the main loop.
__global__ __launch_bounds__(512, 2) void k_gemm(const unsigned short* __restrict__ Ahi,
                                                 const unsigned short* __restrict__ Bcb,
                                                 const float* __restrict__ csq,
                                                 float* __restrict__ partD,   // [NROWS][64]
                                                 int* __restrict__ partI) {
    __shared__ __align__(16) char lds[131072];   // 4 buffers x (A 16KB | B 16KB)
    __shared__ float csqS[256];

    const int tid = threadIdx.x;
    const int lane = tid & 63;
    const int w = tid >> 6;
    const int wr = w >> 2;      // 0..1 : 128-row half
    const int wc = w & 3;       // 0..3 : 64-col quarter

    // XCD-aware decode (validated r5-r7): 1024 blocks = 8 bin tiles x (8 xcd x 16 panels)
    const int wg = blockIdx.x;
    const int panel = (wg & 7) * 16 + ((wg >> 3) & 15);   // 0..127
    const int T = wg >> 7;                                 // 0..7

    // csq prefetch into a register; pinned as the OLDEST vmem op so the
    // manual vmcnt accounting below stays exact.
    float cval = csq[T * 256 + (tid & 255)];
    __builtin_amdgcn_sched_barrier(0);

    const char* Abase = (const char*)(Ahi + (size_t)panel * 256 * DIM);
    const char* Bbase = (const char*)(Bcb + (size_t)T * 256 * DIM);

    // staging constants: per K-tile each matrix is [256 rows][64B]; 1024 chunks,
    // 2 per thread (L0=tid, L1=tid+512). Chunk swizzle (cc ^ (row&3)) applied on
    // the GLOBAL source; LDS dest linear (both-sides rule).
    const int r0 = tid >> 2, cc0 = tid & 3;
    const int r1 = (tid + 512) >> 2;                 // cc1 == cc0
    const size_t ga0 = (size_t)r0 * (DIM * 2) + ((cc0 ^ (r0 & 3)) << 4);
    const size_t ga1 = (size_t)r1 * (DIM * 2) + ((cc0 ^ (r1 & 3)) << 4);
    const int ld0 = tid * 16;
    const int ld1 = ld0 + 8192;

    // prologue: stage tiles 0,1,2 (12 loads/thread)
#pragma unroll
    for (int tt = 0; tt < 3; ++tt) {
        char* buf = lds + tt * 32768;
        const int k0b = tt * 64;
        gload16(Abase + ga0 + k0b, buf + ld0);
        gload16(Abase + ga1 + k0b, buf + ld1);
        gload16(Bbase + ga0 + k0b, buf + 16384 + ld0);
        gload16(Bbase + ga1 + k0b, buf + 16384 + ld1);
    }
    __builtin_amdgcn_sched_barrier(0);

    // fragment read constants (swizzled): row&3 == lane&3 for all frag rows
    const int swz = (((lane >> 4) ^ (lane & 3)) << 4);
    const int aoff = (wr * 128 + (lane & 15)) * 64 + swz;
    const int boff = (wc * 64 + (lane & 15)) * 64 + swz;

    f32x4 acc[8][4];
#pragma unroll
    for (int m = 0; m < 8; ++m)
#pragma unroll
        for (int n = 0; n < 4; ++n) acc[m][n] = (f32x4){0.f, 0.f, 0.f, 0.f};

#pragma unroll 1
    for (int t = 0; t < 16; ++t) {
        // own tile-t loads complete when <= 4*(tiles issued after t) outstanding
        if (t <= 13)      asm volatile("s_waitcnt vmcnt(8)" ::: "memory");
        else if (t == 14) asm volatile("s_waitcnt vmcnt(4)" ::: "memory");
        else              asm volatile("s_waitcnt vmcnt(0)" ::: "memory");
        __builtin_amdgcn_s_barrier();          // all waves: tile t ready, tile t-1 reads done
        __builtin_amdgcn_sched_barrier(0);

        if (t <= 12) {                         // stage tile t+3 into freed buffer
            char* buf = lds + ((t + 3) & 3) * 32768;
            const int k0b = (t + 3) * 64;
            gload16(Abase + ga0 + k0b, buf + ld0);
            gload16(Abase + ga1 + k0b, buf + ld1);
            gload16(Bbase + ga0 + k0b, buf + 16384 + ld0);
            gload16(Bbase + ga1 + k0b, buf + 16384 + ld1);
        }

        const char* bufA = lds + (t & 3) * 32768;
        const char* bufB = bufA + 16384;
        short8v bF[4];
#pragma unroll
        for (int n = 0; n < 4; ++n)
            bF[n] = *(const short8v*)(bufB + boff + n * 1024);
        __builtin_amdgcn_s_setprio(1);
#pragma unroll
        for (int m = 0; m < 8; ++m) {
            short8v aF = *(const short8v*)(bufA + aoff + m * 1024);
#pragma unroll
            for (int n = 0; n < 4; ++n)
                acc[m][n] = __builtin_amdgcn_mfma_f32_16x16x32_bf16(
                    aF, bF[n], acc[m][n], 0, 0, 0);
        }
        __builtin_amdgcn_s_setprio(0);
    }
    __builtin_amdgcn_sched_barrier(0);

    if (tid < 256) csqS[tid] = cval;

    // epilogue (validated r7 pattern): 4 phases through a [256][66] f32 LDS
    // tile reusing the staging LDS. Thread (row2,h) keeps a running top-4 over
    // its 128 scanned cols; two top-4s per row per 256-bin tile stored.
    float td0 = 3.4e38f, td1 = 3.4e38f, td2 = 3.4e38f, td3 = 3.4e38f;
    int ti0 = 0, ti1 = 0, ti2 = 0, ti3 = 0;
    float* distf = (float*)lds;
    const int row2 = tid >> 1, h = tid & 1;

#pragma unroll
    for (int p = 0; p < 4; ++p) {
        __syncthreads();
        if (wc == p) {
#pragma unroll
            for (int m = 0; m < 8; ++m)
#pragma unroll
                for (int n = 0; n < 4; ++n)
#pragma unroll
                    for (int r = 0; r < 4; ++r) {
                        int row = wr * 128 + m * 16 + (lane >> 4) * 4 + r;
                        int cl = n * 16 + (lane & 15);
                        distf[row * 66 + cl] = csqS[p * 64 + cl] - 2.0f * acc[m][n][r];
                    }
        }
        __syncthreads();
        int binb = T * 256 + p * 64 + h * 32;
        for (int c = 0; c < 32; ++c) {
            float d = distf[row2 * 66 + h * 32 + c];
            int bin = binb + c;
            if (d < td3) {
                if (d < td2) {
                    td3 = td2; ti3 = ti2;
                    if (d < td1) {
                        td2 = td1; ti2 = ti1;
                        if (d < td0) { td1 = td0; ti1 = ti0; td0 = d; ti0 = bin; }
                        else { td1 = d; ti1 = bin; }
                    } else { td2 = d; ti2 = bin; }
                } else { td3 = d; ti3 = bin; }
            }
        }
    }
    size_t g = ((size_t)panel * 256 + row2) * 64 + T * 8 + h * 4;
    partD[g + 0] = td0; partI[g + 0] = ti0;
    partD[g + 1] = td1; partI[g + 1] = ti1;
    partD[g + 2] = td2; partI[g + 2] = ti2;
    partD[g + 3] = td3; partI[g + 3] = ti3;
}

// ---------------------------------------------------------------------------
// fused phase-2: resolve argmin (validated margin/exact path) then update the
// residual + rsq + bf16 copy, one 128-thread block per row. (Validated r8-r10.)
__global__ __launch_bounds__(128) void k_ru(const float* __restrict__ partD,
                                            const int* __restrict__ partI,
                                            float* __restrict__ resid,      // in/out
                                            float* __restrict__ rsq,        // in/out
                                            const float* __restrict__ csq,  // stage [NBINS]
                                            const float* __restrict__ cb,   // stage fp32
                                            float* __restrict__ codeOut,
                                            unsigned short* __restrict__ ahi) {
    const int row = blockIdx.x;
    const int t = threadIdx.x;
    __shared__ int sIdx;
    __shared__ float sq[DIM];

    if (t < 64) {
        float d = partD[(size_t)row * 64 + t];
        int bi0 = partI[(size_t)row * 64 + t];

        float bd = d; int bix = bi0;
#pragma unroll
        for (int o = 32; o > 0; o >>= 1) {
            float od = __shfl_xor(bd, o);
            int oi = __shfl_xor(bix, o);
            if (od < bd || (od == bd && oi < bix)) { bd = od; bix = oi; }
        }
        bool cand = (d <= bd + MARGIN);
        unsigned long long mask = __ballot(cand);
        int winI;
        if (__popcll(mask) == 1) {
            winI = bix;
        } else {
            float myD = 3.4e38f; int myI = 0x7fffffff;
            if (cand) {
                const float* rp = resid + (size_t)row * DIM;
                const float* cp = cb + (size_t)bi0 * DIM;
                float acc = 0.0f;
                for (int k = 0; k < DIM; k += 4) {
                    float4 rv = *(const float4*)(rp + k);
                    float4 cv = *(const float4*)(cp + k);
                    acc = fmaf(rv.x, cv.x, acc);
                    acc = fmaf(rv.y, cv.y, acc);
                    acc = fmaf(rv.z, cv.z, acc);
                    acc = fmaf(rv.w, cv.w, acc);
                }
                myD = __fadd_rn(__fsub_rn(rsq[row], __fmul_rn(2.0f, acc)), csq[bi0]);
                myI = bi0;
            }
#pragma unroll
            for (int o = 32; o > 0; o >>= 1) {
                float od = __shfl_xor(myD, o);
                int oi = __shfl_xor(myI, o);
                if (od < myD || (od == myD && oi < myI)) { myD = od; myI = oi; }
            }
            winI = myI;
        }
        if (t == 0) {
            sIdx = winI;
            codeOut[row] = (float)winI;
        }
    }
    __syncthreads();
    const int id = sIdx;

    // exact fp32 residual update + np-exact rsq + bf16 copy (validated round 4)
    float4 r = *(const float4*)(resid + (size_t)row * DIM + t * 4);
    float4 c = *(const float4*)(cb + (size_t)id * DIM + t * 4);
    r.x = __fsub_rn(r.x, c.x);
    r.y = __fsub_rn(r.y, c.y);
    r.z = __fsub_rn(r.z, c.z);
    r.w = __fsub_rn(r.w, c.w);
    *(float4*)(resid + (size_t)row * DIM + t * 4) = r;
    ushort4 hv;
    hv.x = f2bf(r.x); hv.y = f2bf(r.y); hv.z = f2bf(r.z); hv.w = f2bf(r.w);
    *(ushort4*)(ahi + (size_t)row * DIM + t * 4) = hv;

    sq[t * 4 + 0] = __fmul_rn(r.x, r.x);
    sq[t * 4 + 1] = __fmul_rn(r.y, r.y);
    sq[t * 4 + 2] = __fmul_rn(r.z, r.z);
    sq[t * 4 + 3] = __fmul_rn(r.w, r.w);
    __syncthreads();
    if (t < 32) {
        int base = (t >> 3) * 128 + (t & 7);
        float s = sq[base];
#pragma unroll
        for (int m = 1; m < 16; ++m) s = __fadd_rn(s, sq[base + 8 * m]);
        s = pw_combine(s);
        if (t == 0) rsq[row] = s;
    }
}

// ---------------------------------------------------------------------------
// quantized = hidden - residual, IN PLACE (residual lives in the quant region)
__global__ __launch_bounds__(256) void k_quant(const float* __restrict__ h,
                                               float* __restrict__ q) {
    size_t base = ((size_t)blockIdx.x * 256 + threadIdx.x) * 4;
    float4 rv = *(const float4*)(q + base);
    float4 hv = *(const float4*)(h + base);
    float4 o;
    o.x = __fsub_rn(hv.x, rv.x);
    o.y = __fsub_rn(hv.y, rv.y);
    o.z = __fsub_rn(hv.z, rv.z);
    o.w = __fsub_rn(hv.w, rv.w);
    *(float4*)(q + base) = o;
}

// ---------------------------------------------------------------------------
extern "C" void kernel_launch(void* const* d_in, const int* in_sizes, int n_in,
                              void* d_out, int out_size, void* d_ws, size_t ws_size,
                              hipStream_t stream) {
    const float* hidden = (const float*)d_in[0];   // [NROWS][DIM]
    const float* cbs = (const float*)d_in[1];      // [NQ][NBINS][DIM]

    float* out_codes = (float*)d_out;                          // [NQ][NROWS]
    float* resid = out_codes + (size_t)NQ * NROWS;             // quant region doubles as residual

    // workspace (~67 MB)
    unsigned short* Ahi = (unsigned short*)d_ws;               // NROWS*DIM bf16
    unsigned short* Cbf = Ahi + (size_t)NROWS * DIM;           // NQ*NBINS*DIM bf16
    float* csq32 = (float*)(Cbf + (size_t)NQ * NBINS * DIM);   // NQ*NBINS
    float* rsq = csq32 + (size_t)NQ * NBINS;                   // NROWS
    float* partD = rsq + NROWS;                                // NROWS*64
    int* partI = (int*)(partD + (size_t)NROWS * 64);           // NROWS*64

    k_csq<<<NQ * NBINS / 4, 256, 0, stream>>>(cbs, csq32);
    k_cbf<<<(int)((size_t)NQ * NBINS * DIM / 8 / 256), 256, 0, stream>>>(cbs, Cbf);
    k_init<<<NROWS, 128, 0, stream>>>(hidden, resid, rsq, Ahi);

    for (int s = 0; s < NQ; ++s) {
        const float* cbS = cbs + (size_t)s * NBINS * DIM;
        k_gemm<<<(NROWS / 256) * (NBINS / 256), 512, 0, stream>>>(
            Ahi, Cbf + (size_t)s * NBINS * DIM, csq32 + (size_t)s * NBINS,
            partD, partI);
        k_ru<<<NROWS, 128, 0, stream>>>(partD, partI, resid, rsq,
                                        csq32 + (size_t)s * NBINS, cbS,
                                        out_codes + (size_t)s * NROWS, Ahi);
    }
    k_quant<<<NROWS * DIM / 4 / 256, 256, 0, stream>>>(hidden, resid);
}

// Round 12
// 1221.720 us; speedup vs baseline: 1.2943x; 1.2943x over previous
//
#include <hip/hip_runtime.h>
#include <hip/hip_bf16.h>

#define NROWS 32768
#define DIM   512
#define NQ    8
#define NBINS 2048

#define MARGIN 1.0f        // ~20 sigma of bf16 phase-1 noise (validated rounds 5/7/8/9/10)

typedef __attribute__((ext_vector_type(8))) short short8v;
typedef __attribute__((ext_vector_type(4))) float f32x4;

__device__ inline unsigned short f2bf(float x) {
    __hip_bfloat16 h = __float2bfloat16(x);
    return *reinterpret_cast<unsigned short*>(&h);
}

typedef __attribute__((address_space(3))) void lds_t;
typedef __attribute__((address_space(1))) const void gbl_t;
__device__ inline void gload16(const void* g, void* l) {
    __builtin_amdgcn_global_load_lds((gbl_t*)g, (lds_t*)l, 16, 0, 0);
}

// ---------------------------------------------------------------------------
// numpy pairwise-sum combine (validated round 4)
__device__ inline float pw_combine(float s) {
#pragma unroll
    for (int m = 1; m <= 16; m <<= 1) {
        float o = __shfl_xor(s, m, 64);
        s = __fadd_rn(s, o);
    }
    return s;
}

// ---------------------------------------------------------------------------
// fused prep: codebook fp32 -> bf16 AND csq = np.sum(c*c,-1) (np-exact pairwise,
// validated round 4). One wave per codebook row; row is L1-hot for second pass.
__global__ __launch_bounds__(256) void k_prep(const float* __restrict__ cb,
                                              unsigned short* __restrict__ o,
                                              float* __restrict__ csq32) {
    int row = blockIdx.x * 4 + (threadIdx.x >> 6);
    int lane = threadIdx.x & 63;
    const float* cp = cb + (size_t)row * DIM;

    // conversion: 8 contiguous elements per lane
    float4 a = *(const float4*)(cp + lane * 8);
    float4 b = *(const float4*)(cp + lane * 8 + 4);
    short8v v;
    v[0] = f2bf(a.x); v[1] = f2bf(a.y); v[2] = f2bf(a.z); v[3] = f2bf(a.w);
    v[4] = f2bf(b.x); v[5] = f2bf(b.y); v[6] = f2bf(b.z); v[7] = f2bf(b.w);
    *(short8v*)(o + (size_t)row * DIM + lane * 8) = v;

    // np-exact csq (strided 16-term chains on lanes 0..31, exact round-4 order)
    float s = 0.0f;
    if (lane < 32) {
        int base = (lane >> 3) * 128 + (lane & 7);
        float e = cp[base];
        s = __fmul_rn(e, e);
#pragma unroll
        for (int m = 1; m < 16; ++m) {
            float e2 = cp[base + 8 * m];
            s = __fadd_rn(s, __fmul_rn(e2, e2));
        }
    }
    s = pw_combine(s);
    if (lane == 0) csq32[row] = s;
}

// ---------------------------------------------------------------------------
// initial residual (= hidden) + np-exact rsq + bf16 copy for the MFMA phase.
__global__ __launch_bounds__(128) void k_init(const float* __restrict__ h,
                                              float* __restrict__ rout,
                                              float* __restrict__ rsq,
                                              unsigned short* __restrict__ ahi) {
    int row = blockIdx.x;
    int t = threadIdx.x;
    __shared__ float sq[DIM];
    float4 r = *(const float4*)(h + (size_t)row * DIM + t * 4);
    *(float4*)(rout + (size_t)row * DIM + t * 4) = r;
    ushort4 hv;
    hv.x = f2bf(r.x); hv.y = f2bf(r.y); hv.z = f2bf(r.z); hv.w = f2bf(r.w);
    *(ushort4*)(ahi + (size_t)row * DIM + t * 4) = hv;
    sq[t * 4 + 0] = __fmul_rn(r.x, r.x);
    sq[t * 4 + 1] = __fmul_rn(r.y, r.y);
    sq[t * 4 + 2] = __fmul_rn(r.z, r.z);
    sq[t * 4 + 3] = __fmul_rn(r.w, r.w);
    __syncthreads();
    if (t < 32) {
        int base = (t >> 3) * 128 + (t & 7);
        float s = sq[base];
#pragma unroll
        for (int m = 1; m < 16; ++m) s = __fadd_rn(s, sq[base + 8 * m]);
        s = pw_combine(s);
        if (t == 0) rsq[row] = s;
    }
}

// ---------------------------------------------------------------------------
// phase-1: bf16 MFMA GEMM, 128x128 tile, BK=64, 4 waves x 64x64 out
// (acc[4][4], 2.0 MFMA per ds_read_b128), single-buffered staging, 4 blocks/CU
// (r10 structure, 107us validated). r12 delta: K-loop fully unrolled with
// hoisted staging offsets -- backend folds ks*128 into the load imm offset.
__global__ __launch_bounds__(256, 4) void k_gemm(const unsigned short* __restrict__ Ahi,
                                                 const unsigned short* __restrict__ Bcb,
                                                 const float* __restrict__ csq,
                                                 float* __restrict__ partD,   // [NROWS][64]
                                                 int* __restrict__ partI) {
    __shared__ __align__(16) char lds[33792];   // union: stage A16K|B16K ; dist [128][66] f32
    __shared__ float csqS[128];

    const int tid = threadIdx.x;
    const int lane = tid & 63;
    const int w = tid >> 6;
    const int wr = w >> 1;      // 0..1 : 64-row half
    const int wc = w & 1;       // 0..1 : 64-col half

    // XCD-aware decode (validated r9/r10): 4096 blocks = 16 tiles x (8 xcd x 32 panels)
    const int wg = blockIdx.x;
    const int rem = wg & 255;
    const int panel = (rem & 7) * 32 + (rem >> 3);   // 0..255
    const int T = wg >> 8;                            // 0..15

    if (tid < 128) csqS[tid] = csq[T * 128 + tid];

    const char* Abase = (const char*)(Ahi + (size_t)panel * 128 * DIM);
    const char* Bbase = (const char*)(Bcb + (size_t)T * 128 * DIM);

    // per-i staging offsets (loop-invariant across K-steps): chunk swizzle
    // (cc ^ (row&7)) on the GLOBAL source, LDS dest linear (both-sides rule).
    int goff[4], loff[4];
#pragma unroll
    for (int i = 0; i < 4; ++i) {
        int L = i * 256 + tid;            // 0..1023
        int row = L >> 3, cc = L & 7;
        goff[i] = row * (DIM * 2) + ((cc ^ (row & 7)) << 4);
        loff[i] = L * 16;
    }

    f32x4 acc[4][4];
#pragma unroll
    for (int m = 0; m < 4; ++m)
#pragma unroll
        for (int n = 0; n < 4; ++n) acc[m][n] = (f32x4){0.f, 0.f, 0.f, 0.f};

#pragma unroll
    for (int ks = 0; ks < 8; ++ks) {
        __syncthreads();                   // all waves done reading prev tile
        const int k0b = ks * 128;
#pragma unroll
        for (int i = 0; i < 4; ++i) {
            gload16(Abase + goff[i] + k0b, lds + loff[i]);
            gload16(Bbase + goff[i] + k0b, lds + 16384 + loff[i]);
        }
        __syncthreads();                   // staged tile visible
        __builtin_amdgcn_s_setprio(1);
        const char* Ab = lds;
        const char* Bb = lds + 16384;
#pragma unroll
        for (int kk = 0; kk < 2; ++kk) {
            const int sw = (((kk * 4 + (lane >> 4)) ^ (lane & 7)) << 4);
            short8v bF[4];
#pragma unroll
            for (int n = 0; n < 4; ++n) {
                int rowB = wc * 64 + n * 16 + (lane & 15);
                bF[n] = *(const short8v*)(Bb + rowB * 128 + sw);
            }
#pragma unroll
            for (int m = 0; m < 4; ++m) {
                int rowA = wr * 64 + m * 16 + (lane & 15);
                short8v aF = *(const short8v*)(Ab + rowA * 128 + sw);
#pragma unroll
                for (int n = 0; n < 4; ++n)
                    acc[m][n] = __builtin_amdgcn_mfma_f32_16x16x32_bf16(
                        aF, bF[n], acc[m][n], 0, 0, 0);
            }
        }
        __builtin_amdgcn_s_setprio(0);
    }

    // epilogue (byte-identical to validated r10): 2 phases through [128][66],
    // running top-4 per (row,h), adjacent-lane merge -> top-4 per 128-bin tile.
    float td0 = 3.4e38f, td1 = 3.4e38f, td2 = 3.4e38f, td3 = 3.4e38f;
    int ti0 = 0, ti1 = 0, ti2 = 0, ti3 = 0;
    float* distf = (float*)lds;
    const int row2 = tid >> 1, h = tid & 1;

#pragma unroll
    for (int p = 0; p < 2; ++p) {
        __syncthreads();
        if (wc == p) {
#pragma unroll
            for (int m = 0; m < 4; ++m)
#pragma unroll
                for (int n = 0; n < 4; ++n)
#pragma unroll
                    for (int r = 0; r < 4; ++r) {
                        int row = wr * 64 + m * 16 + (lane >> 4) * 4 + r;
                        int cl = n * 16 + (lane & 15);                 // 0..63
                        distf[row * 66 + cl] = csqS[p * 64 + cl] - 2.0f * acc[m][n][r];
                    }
        }
        __syncthreads();
        int binb = T * 128 + p * 64 + h * 32;
        for (int c = 0; c < 32; ++c) {
            float d = distf[row2 * 66 + h * 32 + c];
            int bin = binb + c;
            if (d < td3) {
                if (d < td2) {
                    td3 = td2; ti3 = ti2;
                    if (d < td1) {
                        td2 = td1; ti2 = ti1;
                        if (d < td0) { td1 = td0; ti1 = ti0; td0 = d; ti0 = bin; }
                        else { td1 = d; ti1 = bin; }
                    } else { td2 = d; ti2 = bin; }
                } else { td3 = d; ti3 = bin; }
            }
        }
    }
#pragma unroll
    for (int j = 0; j < 4; ++j) {
        float d = __shfl_xor(j == 0 ? td0 : (j == 1 ? td1 : (j == 2 ? td2 : td3)), 1);
        int bin = __shfl_xor(j == 0 ? ti0 : (j == 1 ? ti1 : (j == 2 ? ti2 : ti3)), 1);
        if (d < td3) {
            if (d < td2) {
                td3 = td2; ti3 = ti2;
                if (d < td1) {
                    td2 = td1; ti2 = ti1;
                    if (d < td0) { td1 = td0; ti1 = ti0; td0 = d; ti0 = bin; }
                    else { td1 = d; ti1 = bin; }
                } else { td2 = d; ti2 = bin; }
            } else { td3 = d; ti3 = bin; }
        }
    }
    if (h == 0) {
        size_t g = ((size_t)panel * 128 + row2) * 64 + T * 4;
        partD[g + 0] = td0; partI[g + 0] = ti0;
        partD[g + 1] = td1; partI[g + 1] = ti1;
        partD[g + 2] = td2; partI[g + 2] = ti2;
        partD[g + 3] = td3; partI[g + 3] = ti3;
    }
}

// ---------------------------------------------------------------------------
// fused phase-2: resolve argmin (validated margin/exact path), then either
// update residual + rsq + bf16 copy (normal stages) or write the final
// quantized output q = hidden - r_new directly (last stage; replaces k_quant).
__global__ __launch_bounds__(128) void k_ru(const float* __restrict__ partD,
                                            const int* __restrict__ partI,
                                            float* __restrict__ resid,      // in/out (== quant region)
                                            float* __restrict__ rsq,        // in/out
                                            const float* __restrict__ csq,  // stage [NBINS]
                                            const float* __restrict__ cb,   // stage fp32
                                            float* __restrict__ codeOut,
                                            unsigned short* __restrict__ ahi,
                                            const float* __restrict__ hidden,
                                            int last) {
    const int row = blockIdx.x;
    const int t = threadIdx.x;
    __shared__ int sIdx;
    __shared__ float sq[DIM];

    if (t < 64) {
        float d = partD[(size_t)row * 64 + t];
        int bi0 = partI[(size_t)row * 64 + t];

        float bd = d; int bix = bi0;
#pragma unroll
        for (int o = 32; o > 0; o >>= 1) {
            float od = __shfl_xor(bd, o);
            int oi = __shfl_xor(bix, o);
            if (od < bd || (od == bd && oi < bix)) { bd = od; bix = oi; }
        }
        bool cand = (d <= bd + MARGIN);
        unsigned long long mask = __ballot(cand);
        int winI;
        if (__popcll(mask) == 1) {
            winI = bix;
        } else {
            float myD = 3.4e38f; int myI = 0x7fffffff;
            if (cand) {
                const float* rp = resid + (size_t)row * DIM;
                const float* cp = cb + (size_t)bi0 * DIM;
                float acc = 0.0f;
                for (int k = 0; k < DIM; k += 4) {
                    float4 rv = *(const float4*)(rp + k);
                    float4 cv = *(const float4*)(cp + k);
                    acc = fmaf(rv.x, cv.x, acc);
                    acc = fmaf(rv.y, cv.y, acc);
                    acc = fmaf(rv.z, cv.z, acc);
                    acc = fmaf(rv.w, cv.w, acc);
                }
                myD = __fadd_rn(__fsub_rn(rsq[row], __fmul_rn(2.0f, acc)), csq[bi0]);
                myI = bi0;
            }
#pragma unroll
            for (int o = 32; o > 0; o >>= 1) {
                float od = __shfl_xor(myD, o);
                int oi = __shfl_xor(myI, o);
                if (od < myD || (od == myD && oi < myI)) { myD = od; myI = oi; }
            }
            winI = myI;
        }
        if (t == 0) {
            sIdx = winI;
            codeOut[row] = (float)winI;
        }
    }
    __syncthreads();
    const int id = sIdx;

    // exact fp32 residual update (validated round 4)
    float4 r = *(const float4*)(resid + (size_t)row * DIM + t * 4);
    float4 c = *(const float4*)(cb + (size_t)id * DIM + t * 4);
    r.x = __fsub_rn(r.x, c.x);
    r.y = __fsub_rn(r.y, c.y);
    r.z = __fsub_rn(r.z, c.z);
    r.w = __fsub_rn(r.w, c.w);

    if (last) {
        // final stage: emit quantized = hidden - r_new in place (same math as
        // the former k_quant); skip resid/ahi/rsq maintenance.
        float4 hv4 = *(const float4*)(hidden + (size_t)row * DIM + t * 4);
        float4 q;
        q.x = __fsub_rn(hv4.x, r.x);
        q.y = __fsub_rn(hv4.y, r.y);
        q.z = __fsub_rn(hv4.z, r.z);
        q.w = __fsub_rn(hv4.w, r.w);
        *(float4*)(resid + (size_t)row * DIM + t * 4) = q;
        return;
    }

    *(float4*)(resid + (size_t)row * DIM + t * 4) = r;
    ushort4 hv;
    hv.x = f2bf(r.x); hv.y = f2bf(r.y); hv.z = f2bf(r.z); hv.w = f2bf(r.w);
    *(ushort4*)(ahi + (size_t)row * DIM + t * 4) = hv;

    sq[t * 4 + 0] = __fmul_rn(r.x, r.x);
    sq[t * 4 + 1] = __fmul_rn(r.y, r.y);
    sq[t * 4 + 2] = __fmul_rn(r.z, r.z);
    sq[t * 4 + 3] = __fmul_rn(r.w, r.w);
    __syncthreads();
    if (t < 32) {
        int base = (t >> 3) * 128 + (t & 7);
        float s = sq[base];
#pragma unroll
        for (int m = 1; m < 16; ++m) s = __fadd_rn(s, sq[base + 8 * m]);
        s = pw_combine(s);
        if (t == 0) rsq[row] = s;
    }
}

// ---------------------------------------------------------------------------
extern "C" void kernel_launch(void* const* d_in, const int* in_sizes, int n_in,
                              void* d_out, int out_size, void* d_ws, size_t ws_size,
                              hipStream_t stream) {
    const float* hidden = (const float*)d_in[0];   // [NROWS][DIM]
    const float* cbs = (const float*)d_in[1];      // [NQ][NBINS][DIM]

    float* out_codes = (float*)d_out;                          // [NQ][NROWS]
    float* resid = out_codes + (size_t)NQ * NROWS;             // quant region doubles as residual

    // workspace (~67 MB)
    unsigned short* Ahi = (unsigned short*)d_ws;               // NROWS*DIM bf16
    unsigned short* Cbf = Ahi + (size_t)NROWS * DIM;           // NQ*NBINS*DIM bf16
    float* csq32 = (float*)(Cbf + (size_t)NQ * NBINS * DIM);   // NQ*NBINS
    float* rsq = csq32 + (size_t)NQ * NBINS;                   // NROWS
    float* partD = rsq + NROWS;                                // NROWS*64
    int* partI = (int*)(partD + (size_t)NROWS * 64);           // NROWS*64

    k_prep<<<NQ * NBINS / 4, 256, 0, stream>>>(cbs, Cbf, csq32);
    k_init<<<NROWS, 128, 0, stream>>>(hidden, resid, rsq, Ahi);

    for (int s = 0; s < NQ; ++s) {
        const float* cbS = cbs + (size_t)s * NBINS * DIM;
        k_gemm<<<(NROWS / 128) * (NBINS / 128), 256, 0, stream>>>(
            Ahi, Cbf + (size_t)s * NBINS * DIM, csq32 + (size_t)s * NBINS,
            partD, partI);
        k_ru<<<NROWS, 128, 0, stream>>>(partD, partI, resid, rsq,
                                        csq32 + (size_t)s * NBINS, cbS,
                                        out_codes + (size_t)s * NROWS, Ahi,
                                        hidden, s == NQ - 1);
    }
}

// Round 14
// 1216.408 us; speedup vs baseline: 1.2999x; 1.0044x over previous
//
#include <hip/hip_runtime.h>
#include <hip/hip_bf16.h>

#define NROWS 32768
#define DIM   512
#define NQ    8
#define NBINS 2048

#define MARGIN 1.0f        // ~20 sigma of bf16 phase-1 noise (validated rounds 5/7/8/9/10/12)

typedef __attribute__((ext_vector_type(8))) short short8v;
typedef __attribute__((ext_vector_type(4))) float f32x4;

__device__ inline unsigned short f2bf(float x) {
    __hip_bfloat16 h = __float2bfloat16(x);
    return *reinterpret_cast<unsigned short*>(&h);
}

typedef __attribute__((address_space(3))) void lds_t;
typedef __attribute__((address_space(1))) const void gbl_t;
__device__ inline void gload16(const void* g, void* l) {
    __builtin_amdgcn_global_load_lds((gbl_t*)g, (lds_t*)l, 16, 0, 0);
}

// ---------------------------------------------------------------------------
// numpy pairwise-sum combine (validated round 4)
__device__ inline float pw_combine(float s) {
#pragma unroll
    for (int m = 1; m <= 16; m <<= 1) {
        float o = __shfl_xor(s, m, 64);
        s = __fadd_rn(s, o);
    }
    return s;
}

// ---------------------------------------------------------------------------
// fused prep: codebook fp32 -> bf16 AND csq = np.sum(c*c,-1) (np-exact pairwise,
// validated round 4). One wave per codebook row; row is L1-hot for second pass.
__global__ __launch_bounds__(256) void k_prep(const float* __restrict__ cb,
                                              unsigned short* __restrict__ o,
                                              float* __restrict__ csq32) {
    int row = blockIdx.x * 4 + (threadIdx.x >> 6);
    int lane = threadIdx.x & 63;
    const float* cp = cb + (size_t)row * DIM;

    // conversion: 8 contiguous elements per lane
    float4 a = *(const float4*)(cp + lane * 8);
    float4 b = *(const float4*)(cp + lane * 8 + 4);
    short8v v;
    v[0] = f2bf(a.x); v[1] = f2bf(a.y); v[2] = f2bf(a.z); v[3] = f2bf(a.w);
    v[4] = f2bf(b.x); v[5] = f2bf(b.y); v[6] = f2bf(b.z); v[7] = f2bf(b.w);
    *(short8v*)(o + (size_t)row * DIM + lane * 8) = v;

    // np-exact csq (strided 16-term chains on lanes 0..31, exact round-4 order)
    float s = 0.0f;
    if (lane < 32) {
        int base = (lane >> 3) * 128 + (lane & 7);
        float e = cp[base];
        s = __fmul_rn(e, e);
#pragma unroll
        for (int m = 1; m < 16; ++m) {
            float e2 = cp[base + 8 * m];
            s = __fadd_rn(s, __fmul_rn(e2, e2));
        }
    }
    s = pw_combine(s);
    if (lane == 0) csq32[row] = s;
}

// ---------------------------------------------------------------------------
// initial residual (= hidden) + np-exact rsq + bf16 copy for the MFMA phase.
__global__ __launch_bounds__(128) void k_init(const float* __restrict__ h,
                                              float* __restrict__ rout,
                                              float* __restrict__ rsq,
                                              unsigned short* __restrict__ ahi) {
    int row = blockIdx.x;
    int t = threadIdx.x;
    __shared__ float sq[DIM];
    float4 r = *(const float4*)(h + (size_t)row * DIM + t * 4);
    *(float4*)(rout + (size_t)row * DIM + t * 4) = r;
    ushort4 hv;
    hv.x = f2bf(r.x); hv.y = f2bf(r.y); hv.z = f2bf(r.z); hv.w = f2bf(r.w);
    *(ushort4*)(ahi + (size_t)row * DIM + t * 4) = hv;
    sq[t * 4 + 0] = __fmul_rn(r.x, r.x);
    sq[t * 4 + 1] = __fmul_rn(r.y, r.y);
    sq[t * 4 + 2] = __fmul_rn(r.z, r.z);
    sq[t * 4 + 3] = __fmul_rn(r.w, r.w);
    __syncthreads();
    if (t < 32) {
        int base = (t >> 3) * 128 + (t & 7);
        float s = sq[base];
#pragma unroll
        for (int m = 1; m < 16; ++m) s = __fadd_rn(s, sq[base + 8 * m]);
        s = pw_combine(s);
        if (t == 0) rsq[row] = s;
    }
}

// ---------------------------------------------------------------------------
// phase-1: bf16 MFMA GEMM, 128x128 tile, BK=64, 4 waves x 64x64 out
// (acc[4][4], 2.0 MFMA per ds_read_b128), single-buffered staging, 4 blocks/CU
// (validated r10/r12 structure, 108us). dist' = csq - 2*dot~.
__global__ __launch_bounds__(256, 4) void k_gemm(const unsigned short* __restrict__ Ahi,
                                                 const unsigned short* __restrict__ Bcb,
                                                 const float* __restrict__ csq,
                                                 float* __restrict__ partD,   // [NROWS][64]
                                                 int* __restrict__ partI) {
    __shared__ __align__(16) char lds[33792];   // union: stage A16K|B16K ; dist [128][66] f32
    __shared__ float csqS[128];

    const int tid = threadIdx.x;
    const int lane = tid & 63;
    const int w = tid >> 6;
    const int wr = w >> 1;      // 0..1 : 64-row half
    const int wc = w & 1;       // 0..1 : 64-col half

    // XCD-aware decode (validated r9-r12): 4096 blocks = 16 tiles x (8 xcd x 32 panels)
    const int wg = blockIdx.x;
    const int rem = wg & 255;
    const int panel = (rem & 7) * 32 + (rem >> 3);   // 0..255
    const int T = wg >> 8;                            // 0..15

    if (tid < 128) csqS[tid] = csq[T * 128 + tid];

    const char* Abase = (const char*)(Ahi + (size_t)panel * 128 * DIM);
    const char* Bbase = (const char*)(Bcb + (size_t)T * 128 * DIM);

    // per-i staging offsets (loop-invariant across K-steps): chunk swizzle
    // (cc ^ (row&7)) on the GLOBAL source, LDS dest linear (both-sides rule).
    int goff[4], loff[4];
#pragma unroll
    for (int i = 0; i < 4; ++i) {
        int L = i * 256 + tid;            // 0..1023
        int row = L >> 3, cc = L & 7;
        goff[i] = row * (DIM * 2) + ((cc ^ (row & 7)) << 4);
        loff[i] = L * 16;
    }

    f32x4 acc[4][4];
#pragma unroll
    for (int m = 0; m < 4; ++m)
#pragma unroll
        for (int n = 0; n < 4; ++n) acc[m][n] = (f32x4){0.f, 0.f, 0.f, 0.f};

#pragma unroll
    for (int ks = 0; ks < 8; ++ks) {
        __syncthreads();                   // all waves done reading prev tile
        const int k0b = ks * 128;
#pragma unroll
        for (int i = 0; i < 4; ++i) {
            gload16(Abase + goff[i] + k0b, lds + loff[i]);
            gload16(Bbase + goff[i] + k0b, lds + 16384 + loff[i]);
        }
        __syncthreads();                   // staged tile visible
        __builtin_amdgcn_s_setprio(1);
        const char* Ab = lds;
        const char* Bb = lds + 16384;
#pragma unroll
        for (int kk = 0; kk < 2; ++kk) {
            const int sw = (((kk * 4 + (lane >> 4)) ^ (lane & 7)) << 4);
            short8v bF[4];
#pragma unroll
            for (int n = 0; n < 4; ++n) {
                int rowB = wc * 64 + n * 16 + (lane & 15);
                bF[n] = *(const short8v*)(Bb + rowB * 128 + sw);
            }
#pragma unroll
            for (int m = 0; m < 4; ++m) {
                int rowA = wr * 64 + m * 16 + (lane & 15);
                short8v aF = *(const short8v*)(Ab + rowA * 128 + sw);
#pragma unroll
                for (int n = 0; n < 4; ++n)
                    acc[m][n] = __builtin_amdgcn_mfma_f32_16x16x32_bf16(
                        aF, bF[n], acc[m][n], 0, 0, 0);
            }
        }
        __builtin_amdgcn_s_setprio(0);
    }

    // epilogue (validated r10/r12): 2 phases through [128][66], running top-4
    // per (row,h), adjacent-lane merge -> top-4 per row per 128-bin tile.
    float td0 = 3.4e38f, td1 = 3.4e38f, td2 = 3.4e38f, td3 = 3.4e38f;
    int ti0 = 0, ti1 = 0, ti2 = 0, ti3 = 0;
    float* distf = (float*)lds;
    const int row2 = tid >> 1, h = tid & 1;

#pragma unroll
    for (int p = 0; p < 2; ++p) {
        __syncthreads();
        if (wc == p) {
#pragma unroll
            for (int m = 0; m < 4; ++m)
#pragma unroll
                for (int n = 0; n < 4; ++n)
#pragma unroll
                    for (int r = 0; r < 4; ++r) {
                        int row = wr * 64 + m * 16 + (lane >> 4) * 4 + r;
                        int cl = n * 16 + (lane & 15);                 // 0..63
                        distf[row * 66 + cl] = csqS[p * 64 + cl] - 2.0f * acc[m][n][r];
                    }
        }
        __syncthreads();
        int binb = T * 128 + p * 64 + h * 32;
        for (int c = 0; c < 32; ++c) {
            float d = distf[row2 * 66 + h * 32 + c];
            int bin = binb + c;
            if (d < td3) {
                if (d < td2) {
                    td3 = td2; ti3 = ti2;
                    if (d < td1) {
                        td2 = td1; ti2 = ti1;
                        if (d < td0) { td1 = td0; ti1 = ti0; td0 = d; ti0 = bin; }
                        else { td1 = d; ti1 = bin; }
                    } else { td2 = d; ti2 = bin; }
                } else { td3 = d; ti3 = bin; }
            }
        }
    }
#pragma unroll
    for (int j = 0; j < 4; ++j) {
        float d = __shfl_xor(j == 0 ? td0 : (j == 1 ? td1 : (j == 2 ? td2 : td3)), 1);
        int bin = __shfl_xor(j == 0 ? ti0 : (j == 1 ? ti1 : (j == 2 ? ti2 : ti3)), 1);
        if (d < td3) {
            if (d < td2) {
                td3 = td2; ti3 = ti2;
                if (d < td1) {
                    td2 = td1; ti2 = ti1;
                    if (d < td0) { td1 = td0; ti1 = ti0; td0 = d; ti0 = bin; }
                    else { td1 = d; ti1 = bin; }
                } else { td2 = d; ti2 = bin; }
            } else { td3 = d; ti3 = bin; }
        }
    }
    if (h == 0) {
        size_t g = ((size_t)panel * 128 + row2) * 64 + T * 4;
        partD[g + 0] = td0; partI[g + 0] = ti0;
        partD[g + 1] = td1; partI[g + 1] = ti1;
        partD[g + 2] = td2; partI[g + 2] = ti2;
        partD[g + 3] = td3; partI[g + 3] = ti3;
    }
}

// ---------------------------------------------------------------------------
// fused phase-2: resolve argmin (validated margin/exact path), then either
// update residual + rsq + bf16 copy (normal stages) or write the final
// quantized output q = hidden - r_new directly (last stage).
__global__ __launch_bounds__(128) void k_ru(const float* __restrict__ partD,
                                            const int* __restrict__ partI,
                                            float* __restrict__ resid,      // in/out (== quant region)
                                            float* __restrict__ rsq,        // in/out
                                            const float* __restrict__ csq,  // stage [NBINS]
                                            const float* __restrict__ cb,   // stage fp32
                                            float* __restrict__ codeOut,
                                            unsigned short* __restrict__ ahi,
                                            const float* __restrict__ hidden,
                                            int last) {
    const int row = blockIdx.x;
    const int t = threadIdx.x;
    __shared__ int sIdx;
    __shared__ float sq[DIM];

    if (t < 64) {
        float d = partD[(size_t)row * 64 + t];
        int bi0 = partI[(size_t)row * 64 + t];

        float bd = d; int bix = bi0;
#pragma unroll
        for (int o = 32; o > 0; o >>= 1) {
            float od = __shfl_xor(bd, o);
            int oi = __shfl_xor(bix, o);
            if (od < bd || (od == bd && oi < bix)) { bd = od; bix = oi; }
        }
        bool cand = (d <= bd + MARGIN);
        unsigned long long mask = __ballot(cand);
        int winI;
        if (__popcll(mask) == 1) {
            winI = bix;
        } else {
            float myD = 3.4e38f; int myI = 0x7fffffff;
            if (cand) {
                const float* rp = resid + (size_t)row * DIM;
                const float* cp = cb + (size_t)bi0 * DIM;
                float acc = 0.0f;
                for (int k = 0; k < DIM; k += 4) {
                    float4 rv = *(const float4*)(rp + k);
                    float4 cv = *(const float4*)(cp + k);
                    acc = fmaf(rv.x, cv.x, acc);
                    acc = fmaf(rv.y, cv.y, acc);
                    acc = fmaf(rv.z, cv.z, acc);
                    acc = fmaf(rv.w, cv.w, acc);
                }
                myD = __fadd_rn(__fsub_rn(rsq[row], __fmul_rn(2.0f, acc)), csq[bi0]);
                myI = bi0;
            }
#pragma unroll
            for (int o = 32; o > 0; o >>= 1) {
                float od = __shfl_xor(myD, o);
                int oi = __shfl_xor(myI, o);
                if (od < myD || (od == myD && oi < myI)) { myD = od; myI = oi; }
            }
            winI = myI;
        }
        if (t == 0) {
            sIdx = winI;
            codeOut[row] = (float)winI;
        }
    }
    __syncthreads();
    const int id = sIdx;

    // exact fp32 residual update (validated round 4)
    float4 r = *(const float4*)(resid + (size_t)row * DIM + t * 4);
    float4 c = *(const float4*)(cb + (size_t)id * DIM + t * 4);
    r.x = __fsub_rn(r.x, c.x);
    r.y = __fsub_rn(r.y, c.y);
    r.z = __fsub_rn(r.z, c.z);
    r.w = __fsub_rn(r.w, c.w);

    if (last) {
        // final stage: emit quantized = hidden - r_new in place
        float4 hv4 = *(const float4*)(hidden + (size_t)row * DIM + t * 4);
        float4 q;
        q.x = __fsub_rn(hv4.x, r.x);
        q.y = __fsub_rn(hv4.y, r.y);
        q.z = __fsub_rn(hv4.z, r.z);
        q.w = __fsub_rn(hv4.w, r.w);
        *(float4*)(resid + (size_t)row * DIM + t * 4) = q;
        return;
    }

    *(float4*)(resid + (size_t)row * DIM + t * 4) = r;
    ushort4 hv;
    hv.x = f2bf(r.x); hv.y = f2bf(r.y); hv.z = f2bf(r.z); hv.w = f2bf(r.w);
    *(ushort4*)(ahi + (size_t)row * DIM + t * 4) = hv;

    sq[t * 4 + 0] = __fmul_rn(r.x, r.x);
    sq[t * 4 + 1] = __fmul_rn(r.y, r.y);
    sq[t * 4 + 2] = __fmul_rn(r.z, r.z);
    sq[t * 4 + 3] = __fmul_rn(r.w, r.w);
    __syncthreads();
    if (t < 32) {
        int base = (t >> 3) * 128 + (t & 7);
        float s = sq[base];
#pragma unroll
        for (int m = 1; m < 16; ++m) s = __fadd_rn(s, sq[base + 8 * m]);
        s = pw_combine(s);
        if (t == 0) rsq[row] = s;
    }
}

// ---------------------------------------------------------------------------
extern "C" void kernel_launch(void* const* d_in, const int* in_sizes, int n_in,
                              void* d_out, int out_size, void* d_ws, size_t ws_size,
                              hipStream_t stream) {
    const float* hidden = (const float*)d_in[0];   // [NROWS][DIM]
    const float* cbs = (const float*)d_in[1];      // [NQ][NBINS][DIM]

    float* out_codes = (float*)d_out;                          // [NQ][NROWS]
    float* resid = out_codes + (size_t)NQ * NROWS;             // quant region doubles as residual

    // workspace (~67 MB)
    unsigned short* Ahi = (unsigned short*)d_ws;               // NROWS*DIM bf16
    unsigned short* Cbf = Ahi + (size_t)NROWS * DIM;           // NQ*NBINS*DIM bf16
    float* csq32 = (float*)(Cbf + (size_t)NQ * NBINS * DIM);   // NQ*NBINS
    float* rsq = csq32 + (size_t)NQ * NBINS;                   // NROWS
    float* partD = rsq + NROWS;                                // NROWS*64
    int* partI = (int*)(partD + (size_t)NROWS * 64);           // NROWS*64

    k_prep<<<NQ * NBINS / 4, 256, 0, stream>>>(cbs, Cbf, csq32);
    k_init<<<NROWS, 128, 0, stream>>>(hidden, resid, rsq, Ahi);

    for (int s = 0; s < NQ; ++s) {
        const float* cbS = cbs + (size_t)s * NBINS * DIM;
        k_gemm<<<(NROWS / 128) * (NBINS / 128), 256, 0, stream>>>(
            Ahi, Cbf + (size_t)s * NBINS * DIM, csq32 + (size_t)s * NBINS,
            partD, partI);
        k_ru<<<NROWS, 128, 0, stream>>>(partD, partI, resid, rsq,
                                        csq32 + (size_t)s * NBINS, cbS,
                                        out_codes + (size_t)s * NROWS, Ahi,
                                        hidden, s == NQ - 1);
    }
}